// Round 2
// baseline (1544.834 us; speedup 1.0000x reference)
//
#include <hip/hip_runtime.h>
#include <hip/hip_bf16.h>

typedef unsigned short u16;
typedef unsigned int   u32;

#define MM 128
#define NN 64
#define EE 32
#define PP 2
#define SS 512
#define BB 8192

typedef short  short8  __attribute__((ext_vector_type(8)));
typedef short  short4_ __attribute__((ext_vector_type(4)));
typedef float  float4_ __attribute__((ext_vector_type(4)));

__device__ __forceinline__ u16 f2bf(float f) {
    union { float f; u32 i; } v; v.f = f;
    u32 x = v.i;
    return (u16)((x + 0x7fffu + ((x >> 16) & 1u)) >> 16);
}

// ---------------------------------------------------------------------------
// K0: convert Wx (f32, E*M*M) to bf16 scratch for K4's MFMA fragments
// ---------------------------------------------------------------------------
__global__ __launch_bounds__(256) void k0_cvt(
    const float* __restrict__ wx, u16* __restrict__ wxb)
{
    int i = (blockIdx.x * 256 + threadIdx.x) * 4;
    float4 v = *(const float4*)(wx + i);
    short4_ o;
    o[0] = (short)f2bf(v.x); o[1] = (short)f2bf(v.y);
    o[2] = (short)f2bf(v.z); o[3] = (short)f2bf(v.w);
    *(short4_*)(wxb + i) = o;
}

// ---------------------------------------------------------------------------
// K1: z_cur[n][b] = sum_m D[n,m]*z[m,b] + sigma[n]*noise[n,b]   (layout [n][B])
// one wave per (n, 64-b group); D row is wave-uniform -> scalar loads
// ---------------------------------------------------------------------------
__global__ __launch_bounds__(256) void k1_zcur(
    const float* __restrict__ z, const float* __restrict__ noise,
    const float* __restrict__ D, const float* __restrict__ sigma,
    float* __restrict__ zc)
{
    int tid  = threadIdx.x;
    int lane = tid & 63;
    int wid  = blockIdx.x * 4 + (tid >> 6);
    int n    = __builtin_amdgcn_readfirstlane(wid & 63);
    int b    = ((wid >> 6) << 6) + lane;

    const float* Drow = D + n * MM;
    float acc = 0.f;
    #pragma unroll 8
    for (int m = 0; m < MM; ++m)
        acc += Drow[m] * z[m * BB + b];
    acc += sigma[n] * noise[n * BB + b];
    zc[n * BB + b] = acc;
}

// ---------------------------------------------------------------------------
// K2: single pass over context (1 GiB) with online softmax over s.
// One wave handles 4 b's: 16 lanes per b, 4 channels (float4) per lane.
// Outputs u0t[b][64], u1t[b][64]: attn-weighted ctx[s] / ctx[s+1], normalized.
// ---------------------------------------------------------------------------
__global__ __launch_bounds__(256) void k2_stream(
    const float* __restrict__ ctx, const float* __restrict__ zc,
    const float* __restrict__ temp1,
    float* __restrict__ u0t, float* __restrict__ u1t)
{
    int tid  = threadIdx.x;
    int lane = tid & 63;
    int wid  = blockIdx.x * 4 + (tid >> 6);
    int b    = wid * 4 + (lane >> 4);
    int li   = lane & 15;

    const float4* p = (const float4*)ctx;
    const u32 stride = (u32)BB * 16u;          // float4s per s-slice
    u32 base = (u32)b * 16u + (u32)li;

    float zc0 = zc[(4 * li + 0) * BB + b];
    float zc1 = zc[(4 * li + 1) * BB + b];
    float zc2 = zc[(4 * li + 2) * BB + b];
    float zc3 = zc[(4 * li + 3) * BB + b];

    float t1    = fabsf(temp1[0]);
    float scale = 1.4426950408889634f / t1;    // log2(e)/|t1|  (softmax in base 2)

    float4 buf[8];
    #pragma unroll
    for (int j = 0; j < 8; ++j) buf[j] = p[base + (u32)j * stride];
    const float4* pr = p + ((size_t)base + 8u * (size_t)stride);

    float mlog = -3.0e38f;
    float l = 0.f;
    float u00 = 0.f, u01 = 0.f, u02 = 0.f, u03 = 0.f;
    float u10 = 0.f, u11 = 0.f, u12 = 0.f, u13 = 0.f;

    auto step = [&](float4 c, float4 nx) {
        float d = fabsf(c.x - zc0) + fabsf(c.y - zc1)
                + fabsf(c.z - zc2) + fabsf(c.w - zc3);
        d += __shfl_xor(d, 1);
        d += __shfl_xor(d, 2);
        d += __shfl_xor(d, 4);
        d += __shfl_xor(d, 8);                 // sum over the 16-lane group
        float logit = -d * scale;
        float nm    = fmaxf(mlog, logit);
        float alpha = exp2f(mlog - nm);
        float w     = exp2f(logit - nm);
        l   = fmaf(l, alpha, w);
        u00 = fmaf(u00, alpha, w * c.x);
        u01 = fmaf(u01, alpha, w * c.y);
        u02 = fmaf(u02, alpha, w * c.z);
        u03 = fmaf(u03, alpha, w * c.w);
        u10 = fmaf(u10, alpha, w * nx.x);
        u11 = fmaf(u11, alpha, w * nx.y);
        u12 = fmaf(u12, alpha, w * nx.z);
        u13 = fmaf(u13, alpha, w * nx.w);
        mlog = nm;
    };

    // steps s = 0..503, refilling slice s+8 (max refill slice = 511, in-bounds)
    for (int sb = 0; sb < 504; sb += 8) {
        #pragma unroll
        for (int j = 0; j < 8; ++j) {
            float4 c  = buf[j];
            float4 nx = buf[(j + 1) & 7];      // j==7 reads slice sb+8 (refilled at j=0)
            buf[j] = pr[0]; pr += stride;
            step(c, nx);
        }
    }
    // tail: steps 504..510 use slices 504..511 already in the ring
    #pragma unroll
    for (int j = 0; j < 7; ++j) step(buf[j], buf[j + 1]);

    float rl = 1.0f / l;
    float4* o0 = (float4*)(u0t + b * NN);
    float4* o1 = (float4*)(u1t + b * NN);
    o0[li] = make_float4(u00 * rl, u01 * rl, u02 * rl, u03 * rl);
    o1[li] = make_float4(u10 * rl, u11 * rl, u12 * rl, u13 * rl);
}

// ---------------------------------------------------------------------------
// K3: per-b: emb = cw0@u0 + cw1@u1 + cb ; MLP ; softmax over E -> wexp[b][e]
// one wave per b; cross-lane broadcasts via shfl
// ---------------------------------------------------------------------------
__global__ __launch_bounds__(256) void k3_mlp(
    const float* __restrict__ z,
    const float* __restrict__ u0t, const float* __restrict__ u1t,
    const float* __restrict__ convw, const float* __restrict__ convb,
    const float* __restrict__ W1, const float* __restrict__ b1,
    const float* __restrict__ W2, const float* __restrict__ b2,
    const float* __restrict__ temp2, float* __restrict__ wexp)
{
    int tid  = threadIdx.x;
    int lane = tid & 63;
    int b    = blockIdx.x * 4 + (tid >> 6);

    float u0  = u0t[b * NN + lane];
    float u1  = u1t[b * NN + lane];
    float zlo = z[lane * BB + b];
    float zhi = z[(lane + 64) * BB + b];

    // emb for channel o = lane ; conv_w[o][i][0..1] is a float2
    const float2* cw = (const float2*)convw;
    float emb = convb[lane];
    #pragma unroll 8
    for (int i = 0; i < NN; ++i) {
        float2 pr = cw[lane * NN + i];
        emb += pr.x * __shfl(u0, i) + pr.y * __shfl(u1, i);
    }

    int e = lane & 31;                         // lanes 32-63 duplicate (harmless)
    const float* w1r = W1 + e * (MM + NN);
    float h1 = b1[e];
    #pragma unroll 8
    for (int i = 0; i < 64; ++i) h1 += w1r[i]       * __shfl(emb, i);
    #pragma unroll 8
    for (int i = 0; i < 64; ++i) h1 += w1r[64 + i]  * __shfl(zlo, i);
    #pragma unroll 8
    for (int i = 0; i < 64; ++i) h1 += w1r[128 + i] * __shfl(zhi, i);
    h1 = fmaxf(h1, 0.f);

    const float* w2r = W2 + e * EE;
    float h2 = b2[e];
    #pragma unroll 8
    for (int j = 0; j < EE; ++j) h2 += w2r[j] * __shfl(h1, j);

    float t2 = fabsf(temp2[0]);
    float logit = -h2 * (1.4426950408889634f / t2);
    float mx = logit;
    mx = fmaxf(mx, __shfl_xor(mx, 16));
    mx = fmaxf(mx, __shfl_xor(mx, 8));
    mx = fmaxf(mx, __shfl_xor(mx, 4));
    mx = fmaxf(mx, __shfl_xor(mx, 2));
    mx = fmaxf(mx, __shfl_xor(mx, 1));
    float w = exp2f(logit - mx);
    float sm = w;
    sm += __shfl_xor(sm, 16);
    sm += __shfl_xor(sm, 8);
    sm += __shfl_xor(sm, 4);
    sm += __shfl_xor(sm, 2);
    sm += __shfl_xor(sm, 1);
    float wv = w / sm;
    if (lane < 32) wexp[b * EE + lane] = wv;
}

// ---------------------------------------------------------------------------
// K4: out[m,b] = sum_e wexp[e,b] * ( A[e,m]*z[m,b] + (Wx[e]@zcat)[m,b] + h[e,m] )
// MFMA 16x16x32 bf16. Block = 32-b tile, all 128 m (wave w -> m in [32w,32w+32)).
// zcat staged transposed in LDS (+8 pad); A/h terms via two K=32 MFMAs vs wexp^T.
// ---------------------------------------------------------------------------
__global__ __launch_bounds__(256) void k4_experts(
    const float* __restrict__ z, const float* __restrict__ A,
    const u16* __restrict__ Wxb, const float* __restrict__ hexp,
    const float* __restrict__ wexp, float* __restrict__ out)
{
    __shared__ u16   zcl[32][136];   // [b_local][k], +8 pad keeps 16B align, kills conflicts
    __shared__ float wxl[32][33];    // [b_local][e], +1 pad

    int tid = threadIdx.x;
    int b0  = blockIdx.x * 32;

    #pragma unroll
    for (int r = 0; r < 16; ++r) {   // stage zcat tile (relu on last P rows)
        int idx = r * 256 + tid;
        int k = idx >> 5, j = idx & 31;
        float v = z[k * BB + b0 + j];
        if (k >= MM - PP) v = fmaxf(v, 0.f);
        zcl[j][k] = f2bf(v);
    }
    #pragma unroll
    for (int r = 0; r < 4; ++r) {    // stage wexp tile (contiguous [b][e] layout)
        int idx = r * 256 + tid;
        int j = idx >> 5, e = idx & 31;
        wxl[j][e] = wexp[(b0 + j) * EE + e];
    }
    __syncthreads();

    int lane = tid & 63;
    int wv   = tid >> 6;
    int quad = lane >> 4;
    int l15  = lane & 15;
    int mbase = wv * 32;

    float4_ macc[2][2];
    #pragma unroll
    for (int mt = 0; mt < 2; ++mt)
        #pragma unroll
        for (int bt = 0; bt < 2; ++bt)
            macc[mt][bt] = (float4_){0.f, 0.f, 0.f, 0.f};

    for (int e = 0; e < EE; ++e) {
        const u16* wxe = Wxb + e * MM * MM;
        short8 af[2][4];
        #pragma unroll
        for (int mt = 0; mt < 2; ++mt) {
            const u16* rowp = wxe + (mbase + mt * 16 + l15) * MM + quad * 8;
            #pragma unroll
            for (int kt = 0; kt < 4; ++kt)
                af[mt][kt] = *((const short8*)(rowp + kt * 32));
        }
        short8 bfr[2][4];
        #pragma unroll
        for (int bt = 0; bt < 2; ++bt) {
            const u16* lp = &zcl[bt * 16 + l15][quad * 8];
            #pragma unroll
            for (int kt = 0; kt < 4; ++kt)
                bfr[bt][kt] = *((const short8*)(lp + kt * 32));
        }
        #pragma unroll
        for (int mt = 0; mt < 2; ++mt) {
            #pragma unroll
            for (int bt = 0; bt < 2; ++bt) {
                float4_ acc = {0.f, 0.f, 0.f, 0.f};
                #pragma unroll
                for (int kt = 0; kt < 4; ++kt)
                    acc = __builtin_amdgcn_mfma_f32_16x16x32_bf16(af[mt][kt], bfr[bt][kt], acc, 0, 0, 0);
                float ws0 = wxl[bt * 16 + l15][e];
                #pragma unroll
                for (int r = 0; r < 4; ++r)
                    macc[mt][bt][r] += acc[r] * ws0;
            }
        }
    }

    // SA = A^T @ wexp^T and Sh = h^T @ wexp^T  (K = E = 32, one MFMA each)
    short8 wf[2];
    #pragma unroll
    for (int bt = 0; bt < 2; ++bt) {
        short8 t;
        #pragma unroll
        for (int j = 0; j < 8; ++j)
            t[j] = (short)f2bf(wxl[bt * 16 + l15][quad * 8 + j]);
        wf[bt] = t;
    }
    short8 atf[2], htf[2];
    #pragma unroll
    for (int mt = 0; mt < 2; ++mt) {
        int m = mbase + mt * 16 + l15;
        short8 ta, th;
        #pragma unroll
        for (int j = 0; j < 8; ++j) {
            int ee = quad * 8 + j;
            ta[j] = (short)f2bf(A[ee * MM + m]);
            th[j] = (short)f2bf(hexp[ee * MM + m]);
        }
        atf[mt] = ta; htf[mt] = th;
    }
    float4_ sa[2][2], sh[2][2];
    #pragma unroll
    for (int mt = 0; mt < 2; ++mt)
        #pragma unroll
        for (int bt = 0; bt < 2; ++bt) {
            float4_ zz = {0.f, 0.f, 0.f, 0.f};
            sa[mt][bt] = __builtin_amdgcn_mfma_f32_16x16x32_bf16(atf[mt], wf[bt], zz, 0, 0, 0);
            sh[mt][bt] = __builtin_amdgcn_mfma_f32_16x16x32_bf16(htf[mt], wf[bt], zz, 0, 0, 0);
        }

    #pragma unroll
    for (int mt = 0; mt < 2; ++mt) {
        #pragma unroll
        for (int bt = 0; bt < 2; ++bt) {
            int bcol = b0 + bt * 16 + l15;
            #pragma unroll
            for (int r = 0; r < 4; ++r) {
                int m = mbase + mt * 16 + quad * 4 + r;
                float zv  = z[m * BB + bcol];
                float val = macc[mt][bt][r] + sa[mt][bt][r] * zv + sh[mt][bt][r];
                out[m * BB + bcol] = val;
            }
        }
    }
}

// ---------------------------------------------------------------------------
extern "C" void kernel_launch(void* const* d_in, const int* in_sizes, int n_in,
                              void* d_out, int out_size, void* d_ws, size_t ws_size,
                              hipStream_t stream)
{
    const float* z     = (const float*)d_in[0];
    const float* ctx   = (const float*)d_in[1];
    const float* noise = (const float*)d_in[2];
    const float* convw = (const float*)d_in[3];
    const float* convb = (const float*)d_in[4];
    const float* D     = (const float*)d_in[5];
    const float* sigma = (const float*)d_in[6];
    const float* temp1 = (const float*)d_in[7];
    const float* W1    = (const float*)d_in[8];
    const float* b1    = (const float*)d_in[9];
    const float* W2    = (const float*)d_in[10];
    const float* b2    = (const float*)d_in[11];
    const float* temp2 = (const float*)d_in[12];
    const float* A     = (const float*)d_in[13];
    const float* Wx    = (const float*)d_in[14];
    const float* hexp  = (const float*)d_in[15];
    float* out = (float*)d_out;

    float* zc   = (float*)d_ws;          // [N][B]      2 MB
    float* u0t  = zc   + NN * BB;        // [B][N]      2 MB
    float* u1t  = u0t  + BB * NN;        // [B][N]      2 MB
    float* wexp = u1t  + BB * NN;        // [B][E]      1 MB
    u16*   wxb  = (u16*)(wexp + BB * EE);// [E][M][M]   1 MB bf16

    k0_cvt   <<< 512, 256, 0, stream>>>(Wx, wxb);
    k1_zcur  <<<2048, 256, 0, stream>>>(z, noise, D, sigma, zc);
    k2_stream<<< 512, 256, 0, stream>>>(ctx, zc, temp1, u0t, u1t);
    k3_mlp   <<<2048, 256, 0, stream>>>(z, u0t, u1t, convw, convb, W1, b1, W2, b2, temp2, wexp);
    k4_experts<<<256, 256, 0, stream>>>(z, A, wxb, hexp, wexp, out);
}